// Round 6
// baseline (379.240 us; speedup 1.0000x reference)
//
#include <hip/hip_runtime.h>
#include <math.h>

#define NN 25600      // total nodes
#define BB 512        // graphs
#define NP 50         // nodes per graph
#define EPG 400       // edges per graph
#define EE 204800     // total edges
#define HH 8
#define CC 64
#define FF 512
#define GRUH 128
#define GRUIN 1024
#define NTP 25664     // hT row stride (25600 + 64 pad)

typedef unsigned short ushort_t;
typedef __attribute__((ext_vector_type(8))) short bf16x8;
typedef __attribute__((ext_vector_type(4))) float f32x4;

__device__ __forceinline__ float wave_reduce_sum(float v) {
  #pragma unroll
  for (int m = 32; m >= 1; m >>= 1) v += __shfl_xor(v, m, 64);
  return v;
}

__device__ __forceinline__ ushort_t f2bf(float x) {
  union { float f; unsigned int u; } v; v.f = x;
  unsigned int r = v.u + 0x7fffu + ((v.u >> 16) & 1u);   // RNE
  return (ushort_t)(r >> 16);
}

__device__ __forceinline__ void gload_lds16(const ushort_t* g, ushort_t* l) {
  __builtin_amdgcn_global_load_lds(
      (const __attribute__((address_space(1))) void*)g,
      (__attribute__((address_space(3))) void*)l, 16, 0, 0);
}

// blocks 0..2: we_dot[l*8+h] = <We_l[h], ae_l[h]>
// block 3: wa[k*8+h] = <W1[k, h*64:..], a_src1[h]>, wa[32+k*8+h] same for a_dst1
__global__ void k_wedot(const float* __restrict__ We1, const float* __restrict__ ae1,
                        const float* __restrict__ We2, const float* __restrict__ ae2,
                        const float* __restrict__ We3, const float* __restrict__ ae3,
                        const float* __restrict__ W1, const float* __restrict__ as1,
                        const float* __restrict__ ad1,
                        float* __restrict__ wdot, float* __restrict__ wa) {
  int head = threadIdx.x >> 6, lane = threadIdx.x & 63;
  if (blockIdx.x < 3) {
    const float* We = blockIdx.x == 0 ? We1 : (blockIdx.x == 1 ? We2 : We3);
    const float* ae = blockIdx.x == 0 ? ae1 : (blockIdx.x == 1 ? ae2 : ae3);
    float v = We[head * 64 + lane] * ae[head * 64 + lane];
    v = wave_reduce_sum(v);
    if (lane == 0) wdot[blockIdx.x * 8 + head] = v;
  } else {
    float as = as1[head * 64 + lane], ad = ad1[head * 64 + lane];
    #pragma unroll
    for (int k = 0; k < 4; k++) {
      float wv = W1[k * 512 + head * 64 + lane];
      float s = wave_reduce_sum(wv * as);
      float d = wave_reduce_sum(wv * ad);
      if (lane == 0) { wa[k * 8 + head] = s; wa[32 + k * 8 + head] = d; }
    }
  }
}

// Per-graph: lattr (mean incoming edge_attr per node) + min/max edge_attr
// (incl. lattr) for the bounded-softmax-max trick.
__global__ void k_lattr(const int* __restrict__ ei, const float* __restrict__ eattr,
                        float* __restrict__ lattr, float* __restrict__ gmm) {
  int g = blockIdx.x, tid = threadIdx.x;
  __shared__ float esum[NP];
  __shared__ int cnt[NP];
  __shared__ unsigned int mn, mx;
  if (tid < NP) { esum[tid] = 0.f; cnt[tid] = 0; }
  if (tid == 0) { mn = 0x7f7fffffu; mx = 0u; }
  __syncthreads();
  for (int e = tid; e < EPG; e += 256) {
    int ge = g * EPG + e;
    int d = ei[EE + ge] - g * NP;
    float a = eattr[ge];                      // a >= 0 by construction
    atomicAdd(&esum[d], a);
    atomicAdd(&cnt[d], 1);
    atomicMax(&mx, __float_as_uint(a));
    atomicMin(&mn, __float_as_uint(a));
  }
  __syncthreads();
  if (tid < NP) {
    float la = esum[tid] / (float)max(cnt[tid], 1);
    lattr[g * NP + tid] = la;
    atomicMax(&mx, __float_as_uint(la));
    atomicMin(&mn, __float_as_uint(la));
  }
  __syncthreads();
  if (tid == 0) { gmm[g * 2] = __uint_as_float(mn); gmm[g * 2 + 1] = __uint_as_float(mx); }
}

// transpose + fp32->bf16: Wt[n][k] = bf16(W[k][n]); K,N multiples of 32
__global__ __launch_bounds__(256) void k_cvt_t(const float* __restrict__ W,
                                               ushort_t* __restrict__ Wt,
                                               int K, int N) {
  __shared__ float t[32][33];
  int n0 = blockIdx.x * 32, k0 = blockIdx.y * 32;
  int tx = threadIdx.x & 31, ty = threadIdx.x >> 5;   // ty 0..7
  #pragma unroll
  for (int i = 0; i < 4; i++)
    t[ty + i * 8][tx] = W[(size_t)(k0 + ty + i * 8) * N + n0 + tx];
  __syncthreads();
  #pragma unroll
  for (int i = 0; i < 4; i++)
    Wt[(size_t)(n0 + ty + i * 8) * K + k0 + tx] = f2bf(t[tx][ty + i * 8]);
}

// layer-1 staging: h1T[f][n] = (x @ W1)^T  (bf16) + exact rank-4 dots.
// grid (50, 8): block = head hd x 512 nodes; 256 threads, 2 consecutive n each.
__global__ __launch_bounds__(256) void k_h1T(
    const float* __restrict__ x, const float* __restrict__ W1,
    const float* __restrict__ wa, ushort_t* __restrict__ hT,
    float* __restrict__ ssg, float* __restrict__ sdg) {
  int hd = blockIdx.y, tid = threadIdx.x;
  int n = blockIdx.x * 512 + tid * 2;
  const float4 x0 = *(const float4*)(x + (size_t)n * 4);
  const float4 x1 = *(const float4*)(x + (size_t)(n + 1) * 4);
  // dots via wa table (exact reassociation of <h1[n], a>)
  float s0 = x0.x * wa[hd] + x0.y * wa[8 + hd] + x0.z * wa[16 + hd] + x0.w * wa[24 + hd];
  float s1 = x1.x * wa[hd] + x1.y * wa[8 + hd] + x1.z * wa[16 + hd] + x1.w * wa[24 + hd];
  float d0 = x0.x * wa[32 + hd] + x0.y * wa[40 + hd] + x0.z * wa[48 + hd] + x0.w * wa[56 + hd];
  float d1 = x1.x * wa[32 + hd] + x1.y * wa[40 + hd] + x1.z * wa[48 + hd] + x1.w * wa[56 + hd];
  ssg[(size_t)n * 8 + hd] = s0; ssg[(size_t)(n + 1) * 8 + hd] = s1;
  sdg[(size_t)n * 8 + hd] = d0; sdg[(size_t)(n + 1) * 8 + hd] = d1;
  #pragma unroll 4
  for (int fi = 0; fi < 64; fi++) {
    int f = hd * 64 + fi;
    float w0 = W1[f], w1 = W1[512 + f], w2 = W1[1024 + f], w3 = W1[1536 + f];
    float h0 = x0.x * w0 + x0.y * w1 + x0.z * w2 + x0.w * w3;
    float h1 = x1.x * w0 + x1.y * w1 + x1.z * w2 + x1.w * w3;
    unsigned int pk = (unsigned int)f2bf(h0) | ((unsigned int)f2bf(h1) << 16);
    *(unsigned int*)(&hT[(size_t)f * NTP + n]) = pk;
  }
}

// Transposed GEMM with fused attention dots:
//   hT[f][n] = sum_k Wt[f][k] * X[n][k]   (bf16 out, fp32 acc)
//   ssg[n*8+hd] = <h[n], a_src[hd]> (exactly-once stores)
__global__ __launch_bounds__(256) void k_bgemmT(
    const ushort_t* __restrict__ Wt, const ushort_t* __restrict__ X,
    const float* __restrict__ a_src, const float* __restrict__ a_dst,
    ushort_t* __restrict__ hT, float* __restrict__ ssg, float* __restrict__ sdg) {
  __shared__ ushort_t As[128 * 32];
  __shared__ ushort_t Bs[128 * 32];
  int tid = threadIdx.x;
  int w = tid >> 6, l = tid & 63;
  int row0 = blockIdx.y * 128;   // feature tile
  int col0 = blockIdx.x * 128;   // node tile
  int wr = w >> 1, wc = w & 1;

  f32x4 acc[4][4];
  #pragma unroll
  for (int i = 0; i < 4; i++)
    #pragma unroll
    for (int j = 0; j < 4; j++) acc[i][j] = (f32x4){0.f, 0.f, 0.f, 0.f};

  int srow = w * 32 + (l >> 2);
  int skcol = (l & 3) * 8;
  const ushort_t* Ag = Wt + (size_t)(row0 + srow) * FF + skcol;
  const ushort_t* Bg = X + (size_t)(col0 + srow) * FF + skcol;
  ushort_t* AsW = &As[w * 1024];
  ushort_t* BsW = &Bs[w * 1024];

  int m_l = l & 15, kq = (l >> 4) * 8;
  const ushort_t* ArdA = &As[(wr * 64 + m_l) * 32 + kq];
  const ushort_t* BrdB = &Bs[(wc * 64 + m_l) * 32 + kq];

  for (int k0 = 0; k0 < FF; k0 += 32) {
    gload_lds16(Ag + k0, AsW);
    gload_lds16(Ag + (size_t)16 * FF + k0, AsW + 512);
    gload_lds16(Bg + k0, BsW);
    gload_lds16(Bg + (size_t)16 * FF + k0, BsW + 512);
    __syncthreads();
    bf16x8 af[4], bfr[4];
    #pragma unroll
    for (int t = 0; t < 4; t++) {
      af[t]  = *(const bf16x8*)(ArdA + t * 16 * 32);
      bfr[t] = *(const bf16x8*)(BrdB + t * 16 * 32);
    }
    #pragma unroll
    for (int mt = 0; mt < 4; mt++)
      #pragma unroll
      for (int nt = 0; nt < 4; nt++)
        acc[mt][nt] = __builtin_amdgcn_mfma_f32_16x16x32_bf16(af[mt], bfr[nt], acc[mt][nt], 0, 0, 0);
    __syncthreads();
  }

  // epilogue: D[m=feature][n=node]; col=lane&15=node, row=quad*4+reg=feature
  int head = (row0 + wr * 64) >> 6;
  int rq = (l >> 4) * 4, cl = l & 15;
  float ds[4] = {0.f, 0.f, 0.f, 0.f}, dd[4] = {0.f, 0.f, 0.f, 0.f};
  #pragma unroll
  for (int mt = 0; mt < 4; mt++) {
    #pragma unroll
    for (int r = 0; r < 4; r++) {
      int f = row0 + wr * 64 + mt * 16 + rq + r;
      float a_s = a_src[f], a_d = a_dst[f];
      #pragma unroll
      for (int nt = 0; nt < 4; nt++) {
        float v = acc[mt][nt][r];
        ds[nt] += v * a_s;
        dd[nt] += v * a_d;
        int n = col0 + wc * 64 + nt * 16 + cl;
        hT[(size_t)f * NTP + n] = f2bf(v);
      }
    }
  }
  #pragma unroll
  for (int nt = 0; nt < 4; nt++) {
    ds[nt] += __shfl_xor(ds[nt], 16, 64); ds[nt] += __shfl_xor(ds[nt], 32, 64);
    dd[nt] += __shfl_xor(dd[nt], 16, 64); dd[nt] += __shfl_xor(dd[nt], 32, 64);
  }
  if (l < 16) {
    #pragma unroll
    for (int nt = 0; nt < 4; nt++) {
      int n = col0 + wc * 64 + nt * 16 + l;
      ssg[(size_t)n * 8 + head] = ds[nt];
      sdg[(size_t)n * 8 + head] = dd[nt];
    }
  }
}

// Unified fused GAT layer (one block per graph,head): ht staged from
// transposed global hT (coalesced, conflict-free LDS), dots precomputed.
// Softmax: bounded-max scatter with fp32 LDS atomics (no CSR).
// If cbf != null (layer 3): fuse agent-gather + graph-mean-pool epilogue.
__global__ __launch_bounds__(256) void k_gatm(
    const ushort_t* __restrict__ hT,
    ushort_t* __restrict__ xout,         // layers 1,2
    ushort_t* __restrict__ cbf,          // layer 3 (pool fused)
    const float* __restrict__ ssg, const float* __restrict__ sdg,
    const int* __restrict__ ei, const float* __restrict__ eattr,
    const float* __restrict__ lattr, const float* __restrict__ gmm,
    const float* __restrict__ wdot_all, const float* __restrict__ bias,
    int layer, int self_loops) {
  int g = blockIdx.x, hd = blockIdx.y, tid = threadIdx.x;
  int w = tid >> 6, lane = tid & 63;

  __shared__ __align__(16) ushort_t ht[64 * 72];   // ht[c][s]
  __shared__ __align__(16) float P[50 * 68];       // scatter accumulator
  __shared__ __align__(16) ushort_t Am[64 * 72];   // alpha bf16 [d][s]
  __shared__ float ssl[64], sdl[64];
  __shared__ float gsum[4 * 64];                   // pool partials

  float wdot = wdot_all[layer * 8 + hd];
  float minEA = gmm[g * 2], maxEA = gmm[g * 2 + 1];
  float cmax = fmaxf(wdot * maxEA, wdot * minEA);
  int m_l = lane & 15, kq8 = (lane >> 4) * 8;

  // stage ht[c][0..63] from hT (cols >= 50 garbage-but-finite; Am cols are 0)
  for (int i = tid; i < 2048; i += 256) {
    int c = i >> 5, q = i & 31;
    *(unsigned int*)(&ht[c * 72 + q * 2]) =
        *(const unsigned int*)(&hT[(size_t)(hd * 64 + c) * NTP + g * NP + q * 2]);
  }
  if (tid < 64) {
    ssl[tid] = (tid < NP) ? ssg[(size_t)(g * NP + tid) * 8 + hd] : -1e30f;
    sdl[tid] = (tid < NP) ? sdg[(size_t)(g * NP + tid) * 8 + hd] : 0.f;
  }
  // zero P (850 uint4 = 13600 B)
  { uint4* z = (uint4*)P; uint4 zz = make_uint4(0u, 0u, 0u, 0u);
    for (int i = tid; i < 850; i += 256) z[i] = zz; }
  __syncthreads();

  // per-wave maxS over ssl
  float mv = ssl[lane];
  #pragma unroll
  for (int m = 32; m >= 1; m >>= 1) mv = fmaxf(mv, __shfl_xor(mv, m, 64));

  // edge scatter: p = exp(lr(al) - m_d), m_d = lr(maxS + sdl[d] + cmax) >= row max
  for (int e = tid; e < EPG; e += 256) {
    int eg = g * EPG + e;
    int s = ei[eg] - g * NP;
    int d = ei[EE + eg] - g * NP;
    float al = ssl[s] + sdl[d] + eattr[eg] * wdot;
    al = al > 0.f ? al : 0.2f * al;
    float ub = mv + sdl[d] + cmax;
    ub = ub > 0.f ? ub : 0.2f * ub;
    atomicAdd(&P[d * 68 + s], __expf(al - ub));
  }
  if (self_loops && tid < NP) {
    int d = tid;
    float al = ssl[d] + sdl[d] + lattr[g * NP + d] * wdot;
    al = al > 0.f ? al : 0.2f * al;
    float ub = mv + sdl[d] + cmax;
    ub = ub > 0.f ? ub : 0.2f * ub;
    atomicAdd(&P[d * 68 + d], __expf(al - ub));
  }
  __syncthreads();

  // normalize -> bf16 Am (rows/cols >= 50 exact zero)
  { int d = tid >> 2, part = tid & 3;
    if (d < NP) {
      f32x4 v0 = *(const f32x4*)(&P[d * 68 + part * 16 + 0]);
      f32x4 v1 = *(const f32x4*)(&P[d * 68 + part * 16 + 4]);
      f32x4 v2 = *(const f32x4*)(&P[d * 68 + part * 16 + 8]);
      f32x4 v3 = *(const f32x4*)(&P[d * 68 + part * 16 + 12]);
      float sm = (v0[0] + v0[1] + v0[2] + v0[3]) + (v1[0] + v1[1] + v1[2] + v1[3])
               + (v2[0] + v2[1] + v2[2] + v2[3]) + (v3[0] + v3[1] + v3[2] + v3[3]);
      sm += __shfl_xor(sm, 1, 64);
      sm += __shfl_xor(sm, 2, 64);
      float inv = 1.f / (sm + 1e-16f);
      union { ushort_t u[8]; uint4 q; } p0, p1;
      p0.u[0] = f2bf(v0[0] * inv); p0.u[1] = f2bf(v0[1] * inv);
      p0.u[2] = f2bf(v0[2] * inv); p0.u[3] = f2bf(v0[3] * inv);
      p0.u[4] = f2bf(v1[0] * inv); p0.u[5] = f2bf(v1[1] * inv);
      p0.u[6] = f2bf(v1[2] * inv); p0.u[7] = f2bf(v1[3] * inv);
      p1.u[0] = f2bf(v2[0] * inv); p1.u[1] = f2bf(v2[1] * inv);
      p1.u[2] = f2bf(v2[2] * inv); p1.u[3] = f2bf(v2[3] * inv);
      p1.u[4] = f2bf(v3[0] * inv); p1.u[5] = f2bf(v3[1] * inv);
      p1.u[6] = f2bf(v3[2] * inv); p1.u[7] = f2bf(v3[3] * inv);
      *(uint4*)(&Am[d * 72 + part * 16]) = p0.q;
      *(uint4*)(&Am[d * 72 + part * 16 + 8]) = p1.q;
    } else {
      uint4 zz = make_uint4(0u, 0u, 0u, 0u);
      *(uint4*)(&Am[d * 72 + part * 16]) = zz;
      *(uint4*)(&Am[d * 72 + part * 16 + 8]) = zz;
    }
  }
  __syncthreads();

  // out MFMA: D[m=c][n=d] = ht @ Am^T; wave w owns d in [w*16, w*16+16)
  int d0 = w * 16;
  f32x4 acc[4];
  #pragma unroll
  for (int ct = 0; ct < 4; ct++) acc[ct] = (f32x4){0.f, 0.f, 0.f, 0.f};
  #pragma unroll
  for (int kc = 0; kc < 2; kc++) {
    int kb = kc * 32 + kq8;
    bf16x8 bfrag = *(const bf16x8*)(&Am[(d0 + m_l) * 72 + kb]);
    #pragma unroll
    for (int ct = 0; ct < 4; ct++) {
      bf16x8 afrag = *(const bf16x8*)(&ht[(ct * 16 + m_l) * 72 + kb]);
      acc[ct] = __builtin_amdgcn_mfma_f32_16x16x32_bf16(afrag, bfrag, acc[ct], 0, 0, 0);
    }
  }

  // bias + relu (C/D layout: row=(lane>>4)*4+reg = c, col=lane&15 = d)
  int d = d0 + m_l, rq = (lane >> 4) * 4;
  bool valid = (d < NP);
  float vv[4][4];
  #pragma unroll
  for (int ct = 0; ct < 4; ct++) {
    const float4 bv = *(const float4*)(&bias[hd * 64 + ct * 16 + rq]);
    vv[ct][0] = fmaxf(acc[ct][0] + bv.x, 0.f);
    vv[ct][1] = fmaxf(acc[ct][1] + bv.y, 0.f);
    vv[ct][2] = fmaxf(acc[ct][2] + bv.z, 0.f);
    vv[ct][3] = fmaxf(acc[ct][3] + bv.w, 0.f);
  }

  if (cbf == nullptr) {
    if (valid) {
      #pragma unroll
      for (int ct = 0; ct < 4; ct++) {
        union { ushort_t u[4]; uint2 v; } pk;
        pk.u[0] = f2bf(vv[ct][0]); pk.u[1] = f2bf(vv[ct][1]);
        pk.u[2] = f2bf(vv[ct][2]); pk.u[3] = f2bf(vv[ct][3]);
        *(uint2*)(&xout[(size_t)(g * NP + d) * FF + hd * 64 + ct * 16 + rq]) = pk.v;
      }
    }
  } else {
    // fused pool: agent rows d<5 -> combined[:512]; mean over d -> combined[512:]
    #pragma unroll
    for (int ct = 0; ct < 4; ct++) {
      #pragma unroll
      for (int r = 0; r < 4; r++) {
        float t = valid ? vv[ct][r] : 0.f;
        t += __shfl_xor(t, 1, 64); t += __shfl_xor(t, 2, 64);
        t += __shfl_xor(t, 4, 64); t += __shfl_xor(t, 8, 64);
        if (m_l == 0) gsum[w * 64 + ct * 16 + rq + r] = t;
      }
    }
    if (w == 0 && m_l < 5) {
      #pragma unroll
      for (int ct = 0; ct < 4; ct++) {
        union { ushort_t u[4]; uint2 v; } pk;
        pk.u[0] = f2bf(vv[ct][0]); pk.u[1] = f2bf(vv[ct][1]);
        pk.u[2] = f2bf(vv[ct][2]); pk.u[3] = f2bf(vv[ct][3]);
        *(uint2*)(&cbf[(size_t)(g * 5 + d) * GRUIN + hd * 64 + ct * 16 + rq]) = pk.v;
      }
    }
    __syncthreads();
    if (tid < 64) {
      float mean = (gsum[tid] + gsum[64 + tid] + gsum[128 + tid] + gsum[192 + tid]) * (1.f / NP);
      ushort_t mb = f2bf(mean);
      #pragma unroll
      for (int t = 0; t < 5; t++)
        cbf[(size_t)(g * 5 + t) * GRUIN + 512 + hd * 64 + tid] = mb;
    }
  }
}

// generic bf16 MFMA GEMM (row-major C fp32) — used for the GRU input GEMM
__global__ __launch_bounds__(256) void k_bgemm(
    const ushort_t* __restrict__ A, const ushort_t* __restrict__ Bt,
    const float* __restrict__ bias, float* __restrict__ C,
    int M, int N, int K) {
  __shared__ ushort_t As[128 * 32];
  __shared__ ushort_t Bs[128 * 32];
  int tid = threadIdx.x;
  int w = tid >> 6, l = tid & 63;
  int row0 = blockIdx.y * 128, col0 = blockIdx.x * 128;
  int wr = w >> 1, wc = w & 1;

  f32x4 acc[4][4];
  #pragma unroll
  for (int i = 0; i < 4; i++)
    #pragma unroll
    for (int j = 0; j < 4; j++) acc[i][j] = (f32x4){0.f, 0.f, 0.f, 0.f};

  int srow = w * 32 + (l >> 2);
  int skcol = (l & 3) * 8;
  const ushort_t* Ag = A + (size_t)(row0 + srow) * K + skcol;
  const ushort_t* Bg = Bt + (size_t)(col0 + srow) * K + skcol;
  ushort_t* AsW = &As[w * 1024];
  ushort_t* BsW = &Bs[w * 1024];

  int m_l = l & 15, kq = (l >> 4) * 8;
  const ushort_t* ArdA = &As[(wr * 64 + m_l) * 32 + kq];
  const ushort_t* BrdB = &Bs[(wc * 64 + m_l) * 32 + kq];

  for (int k0 = 0; k0 < K; k0 += 32) {
    gload_lds16(Ag + k0, AsW);
    gload_lds16(Ag + (size_t)16 * K + k0, AsW + 512);
    gload_lds16(Bg + k0, BsW);
    gload_lds16(Bg + (size_t)16 * K + k0, BsW + 512);
    __syncthreads();
    bf16x8 af[4], bfr[4];
    #pragma unroll
    for (int t = 0; t < 4; t++) {
      af[t]  = *(const bf16x8*)(ArdA + t * 16 * 32);
      bfr[t] = *(const bf16x8*)(BrdB + t * 16 * 32);
    }
    #pragma unroll
    for (int mt = 0; mt < 4; mt++)
      #pragma unroll
      for (int nt = 0; nt < 4; nt++)
        acc[mt][nt] = __builtin_amdgcn_mfma_f32_16x16x32_bf16(af[mt], bfr[nt], acc[mt][nt], 0, 0, 0);
    __syncthreads();
  }

  int cl = l & 15, rq = (l >> 4) * 4;
  #pragma unroll
  for (int mt = 0; mt < 4; mt++) {
    #pragma unroll
    for (int nt = 0; nt < 4; nt++) {
      int col = col0 + wc * 64 + nt * 16 + cl;
      float bv = bias ? bias[col] : 0.f;
      #pragma unroll
      for (int r = 0; r < 4; r++) {
        int row = row0 + wr * 64 + mt * 16 + rq + r;
        C[(size_t)row * N + col] = acc[mt][nt][r] + bv;
      }
    }
  }
}

// GRU: one block per batch element, 5 sequential steps. gi_all already has bih.
__global__ void k_gru(const float* __restrict__ gi_all, const float* __restrict__ h0,
                      const float* __restrict__ Whh, const float* __restrict__ bhh,
                      float* __restrict__ gru_out, float* __restrict__ hlast) {
  int b = blockIdx.x, tid = threadIdx.x;   // 384 threads
  __shared__ float hl[GRUH];
  __shared__ float ghb[384];
  if (tid < GRUH) hl[tid] = h0[b * GRUH + tid];
  for (int t = 0; t < 5; t++) {
    __syncthreads();
    float acc = bhh[tid];
    for (int k = 0; k < GRUH; k++) acc += hl[k] * Whh[k * 384 + tid];
    ghb[tid] = acc;
    __syncthreads();
    if (tid < GRUH) {
      const float* gi = gi_all + (size_t)(b * 5 + t) * 384;
      float r = 1.f / (1.f + expf(-(gi[tid] + ghb[tid])));
      float z = 1.f / (1.f + expf(-(gi[128 + tid] + ghb[128 + tid])));
      float nn = tanhf(gi[256 + tid] + r * ghb[256 + tid]);
      float hn = (1.f - z) * nn + z * hl[tid];
      gru_out[(size_t)(b * 5 + t) * GRUH + tid] = hn;
      hl[tid] = hn;
    }
  }
  __syncthreads();
  if (tid < GRUH) hlast[b * GRUH + tid] = hl[tid];
}

// fc1(relu) + fc2 + action_std, one block (64 thr) per (b,t) row
__global__ void k_fc(const float* __restrict__ gru_out, const float* __restrict__ fc1W,
                     const float* __restrict__ fc1b, const float* __restrict__ fc2W,
                     const float* __restrict__ fc2b, const float* __restrict__ log_std,
                     float* __restrict__ dout) {
  int row = blockIdx.x, tid = threadIdx.x;   // 64 threads
  __shared__ float gbuf[GRUH];
  __shared__ float f1[64];
  gbuf[tid] = gru_out[(size_t)row * GRUH + tid];
  gbuf[tid + 64] = gru_out[(size_t)row * GRUH + 64 + tid];
  __syncthreads();
  float acc = fc1b[tid];
  for (int k = 0; k < GRUH; k++) acc += gbuf[k] * fc1W[k * 64 + tid];
  f1[tid] = fmaxf(acc, 0.f);
  __syncthreads();
  if (tid < 3) {
    float o = fc2b[tid];
    for (int j = 0; j < 64; j++) o += f1[j] * fc2W[j * 3 + tid];
    dout[row * 3 + tid] = o;
    float ls = log_std[tid];
    ls = fminf(fmaxf(ls, -20.f), 2.f);
    dout[7680 + row * 3 + tid] = expf(ls);
  }
}

extern "C" void kernel_launch(void* const* d_in, const int* in_sizes, int n_in,
                              void* d_out, int out_size, void* d_ws, size_t ws_size,
                              hipStream_t stream) {
  const float* x      = (const float*)d_in[0];
  const int*   ei     = (const int*)d_in[1];
  const float* eattr  = (const float*)d_in[2];
  const float* hstate = (const float*)d_in[3];
  const float* W1  = (const float*)d_in[4];
  const float* as1 = (const float*)d_in[5];
  const float* ad1 = (const float*)d_in[6];
  const float* We1 = (const float*)d_in[7];
  const float* ae1 = (const float*)d_in[8];
  const float* b1  = (const float*)d_in[9];
  const float* W2  = (const float*)d_in[10];
  const float* as2 = (const float*)d_in[11];
  const float* ad2 = (const float*)d_in[12];
  const float* We2 = (const float*)d_in[13];
  const float* ae2 = (const float*)d_in[14];
  const float* b2  = (const float*)d_in[15];
  const float* W3  = (const float*)d_in[16];
  const float* as3 = (const float*)d_in[17];
  const float* ad3 = (const float*)d_in[18];
  const float* We3 = (const float*)d_in[19];
  const float* ae3 = (const float*)d_in[20];
  const float* b3  = (const float*)d_in[21];
  const float* Wih = (const float*)d_in[22];
  const float* Whh = (const float*)d_in[23];
  const float* bih = (const float*)d_in[24];
  const float* bhh = (const float*)d_in[25];
  const float* fc1W = (const float*)d_in[26];
  const float* fc1b = (const float*)d_in[27];
  const float* fc2W = (const float*)d_in[28];
  const float* fc2b = (const float*)d_in[29];
  const float* lstd = (const float*)d_in[30];

  float* ws = (float*)d_ws;
  ushort_t* xbf = (ushort_t*)ws;                     // 13,107,200 us
  ushort_t* hT  = (ushort_t*)(ws + 6553600);         // 512*25664 us
  float* p = ws + 6553600 + 6569984;
  float* ssg   = p;           p += 204800;
  float* sdg   = p;           p += 204800;
  float* lattr = p;           p += 25600;
  float* gmm   = p;           p += 1024;
  float* wdot  = p;           p += 32;
  float* wa    = p;           p += 64;
  ushort_t* w2t  = (ushort_t*)p;  p += 131072;   // 262144 us
  ushort_t* w3t  = (ushort_t*)p;  p += 131072;
  ushort_t* wiht = (ushort_t*)p;  p += 196608;   // 393216 us
  ushort_t* cbf  = (ushort_t*)p;  p += 1310720;  // 2,621,440 us
  float* gi_all  = p;         p += 983040;       // [2560][384]
  float* gru_out = p;         p += 327680;
  float* dout = (float*)d_out;

  k_wedot<<<4, 512, 0, stream>>>(We1, ae1, We2, ae2, We3, ae3, W1, as1, ad1, wdot, wa);
  k_lattr<<<BB, 256, 0, stream>>>(ei, eattr, lattr, gmm);
  k_cvt_t<<<dim3(16, 16), 256, 0, stream>>>(W2, w2t, FF, FF);
  k_cvt_t<<<dim3(16, 16), 256, 0, stream>>>(W3, w3t, FF, FF);
  k_cvt_t<<<dim3(12, 32), 256, 0, stream>>>(Wih, wiht, GRUIN, 384);

  // layer 1: h1T = (x@W1)^T + dots (rank-4); gat -> xbf
  k_h1T<<<dim3(50, 8), 256, 0, stream>>>(x, W1, wa, hT, ssg, sdg);
  k_gatm<<<dim3(BB, HH), 256, 0, stream>>>(hT, xbf, nullptr, ssg, sdg, ei, eattr,
                                           lattr, gmm, wdot, b1, 0, 0);
  // layer 2: hT = W2t @ x1^T (+ fused dots); gat -> xbf
  k_bgemmT<<<dim3(200, 4), 256, 0, stream>>>(w2t, xbf, as2, ad2, hT, ssg, sdg);
  k_gatm<<<dim3(BB, HH), 256, 0, stream>>>(hT, xbf, nullptr, ssg, sdg, ei, eattr,
                                           lattr, gmm, wdot, b2, 1, 1);
  // layer 3: gat with fused agent-gather + mean-pool -> cbf
  k_bgemmT<<<dim3(200, 4), 256, 0, stream>>>(w3t, xbf, as3, ad3, hT, ssg, sdg);
  k_gatm<<<dim3(BB, HH), 256, 0, stream>>>(hT, nullptr, cbf, ssg, sdg, ei, eattr,
                                           lattr, gmm, wdot, b3, 2, 1);

  // GRU input GEMM (adds bih)
  k_bgemm<<<dim3(3, 20), 256, 0, stream>>>(cbf, wiht, bih, gi_all, 2560, 384, GRUIN);

  // GRU scan + heads
  k_gru<<<BB, 384, 0, stream>>>(gi_all, hstate, Whh, bhh, gru_out, dout + 15360);
  k_fc<<<2560, 64, 0, stream>>>(gru_out, fc1W, fc1b, fc2W, fc2b, lstd, dout);
}

// Round 7
// 361.685 us; speedup vs baseline: 1.0485x; 1.0485x over previous
//
#include <hip/hip_runtime.h>
#include <math.h>

#define NN 25600      // total nodes
#define BB 512        // graphs
#define NP 50         // nodes per graph
#define EPG 400       // edges per graph
#define EE 204800     // total edges
#define HH 8
#define CC 64
#define FF 512
#define GRUH 128
#define GRUIN 1024
#define NTP 25664     // hT row stride (25600 + 64 pad)

typedef unsigned short ushort_t;
typedef __attribute__((ext_vector_type(8))) short bf16x8;
typedef __attribute__((ext_vector_type(4))) float f32x4;

__device__ __forceinline__ float wave_reduce_sum(float v) {
  #pragma unroll
  for (int m = 32; m >= 1; m >>= 1) v += __shfl_xor(v, m, 64);
  return v;
}

__device__ __forceinline__ ushort_t f2bf(float x) {
  union { float f; unsigned int u; } v; v.f = x;
  unsigned int r = v.u + 0x7fffu + ((v.u >> 16) & 1u);   // RNE
  return (ushort_t)(r >> 16);
}

__device__ __forceinline__ void gload_lds16(const ushort_t* g, ushort_t* l) {
  __builtin_amdgcn_global_load_lds(
      (const __attribute__((address_space(1))) void*)g,
      (__attribute__((address_space(3))) void*)l, 16, 0, 0);
}

// blocks 0..2: we_dot[l*8+h] = <We_l[h], ae_l[h]>
// block 3: wa[k*8+h] = <W1[k, h*64:..], a_src1[h]>, wa[32+k*8+h] same for a_dst1
__global__ void k_wedot(const float* __restrict__ We1, const float* __restrict__ ae1,
                        const float* __restrict__ We2, const float* __restrict__ ae2,
                        const float* __restrict__ We3, const float* __restrict__ ae3,
                        const float* __restrict__ W1, const float* __restrict__ as1,
                        const float* __restrict__ ad1,
                        float* __restrict__ wdot, float* __restrict__ wa) {
  int head = threadIdx.x >> 6, lane = threadIdx.x & 63;
  if (blockIdx.x < 3) {
    const float* We = blockIdx.x == 0 ? We1 : (blockIdx.x == 1 ? We2 : We3);
    const float* ae = blockIdx.x == 0 ? ae1 : (blockIdx.x == 1 ? ae2 : ae3);
    float v = We[head * 64 + lane] * ae[head * 64 + lane];
    v = wave_reduce_sum(v);
    if (lane == 0) wdot[blockIdx.x * 8 + head] = v;
  } else {
    float as = as1[head * 64 + lane], ad = ad1[head * 64 + lane];
    #pragma unroll
    for (int k = 0; k < 4; k++) {
      float wv = W1[k * 512 + head * 64 + lane];
      float s = wave_reduce_sum(wv * as);
      float d = wave_reduce_sum(wv * ad);
      if (lane == 0) { wa[k * 8 + head] = s; wa[32 + k * 8 + head] = d; }
    }
  }
}

// Per-graph: lattr (mean incoming edge_attr), min/max edge_attr (incl lattr)
// for the bounded-softmax-max trick, and packed local edges (d<<6)|s.
__global__ void k_lattr(const int* __restrict__ ei, const float* __restrict__ eattr,
                        float* __restrict__ lattr, float* __restrict__ gmm,
                        ushort_t* __restrict__ epack) {
  int g = blockIdx.x, tid = threadIdx.x;
  __shared__ float esum[NP];
  __shared__ int cnt[NP];
  __shared__ unsigned int mn, mx;
  if (tid < NP) { esum[tid] = 0.f; cnt[tid] = 0; }
  if (tid == 0) { mn = 0x7f7fffffu; mx = 0u; }
  __syncthreads();
  for (int e = tid; e < EPG; e += 256) {
    int ge = g * EPG + e;
    int s = ei[ge] - g * NP;
    int d = ei[EE + ge] - g * NP;
    epack[ge] = (ushort_t)((d << 6) | s);
    float a = eattr[ge];                      // a >= 0 by construction
    atomicAdd(&esum[d], a);
    atomicAdd(&cnt[d], 1);
    atomicMax(&mx, __float_as_uint(a));
    atomicMin(&mn, __float_as_uint(a));
  }
  __syncthreads();
  if (tid < NP) {
    float la = esum[tid] / (float)max(cnt[tid], 1);
    lattr[g * NP + tid] = la;
    atomicMax(&mx, __float_as_uint(la));
    atomicMin(&mn, __float_as_uint(la));
  }
  __syncthreads();
  if (tid == 0) { gmm[g * 2] = __uint_as_float(mn); gmm[g * 2 + 1] = __uint_as_float(mx); }
}

// transpose + fp32->bf16: Wt[n][k] = bf16(W[k][n]); K,N multiples of 32
__global__ __launch_bounds__(256) void k_cvt_t(const float* __restrict__ W,
                                               ushort_t* __restrict__ Wt,
                                               int K, int N) {
  __shared__ float t[32][33];
  int n0 = blockIdx.x * 32, k0 = blockIdx.y * 32;
  int tx = threadIdx.x & 31, ty = threadIdx.x >> 5;   // ty 0..7
  #pragma unroll
  for (int i = 0; i < 4; i++)
    t[ty + i * 8][tx] = W[(size_t)(k0 + ty + i * 8) * N + n0 + tx];
  __syncthreads();
  #pragma unroll
  for (int i = 0; i < 4; i++)
    Wt[(size_t)(n0 + ty + i * 8) * K + k0 + tx] = f2bf(t[tx][ty + i * 8]);
}

// layer-1 staging: h1T[f][n] = (x @ W1)^T  (bf16) + exact rank-4 dots.
__global__ __launch_bounds__(256) void k_h1T(
    const float* __restrict__ x, const float* __restrict__ W1,
    const float* __restrict__ wa, ushort_t* __restrict__ hT,
    float* __restrict__ ssg, float* __restrict__ sdg) {
  int hd = blockIdx.y, tid = threadIdx.x;
  int n = blockIdx.x * 512 + tid * 2;
  const float4 x0 = *(const float4*)(x + (size_t)n * 4);
  const float4 x1 = *(const float4*)(x + (size_t)(n + 1) * 4);
  float s0 = x0.x * wa[hd] + x0.y * wa[8 + hd] + x0.z * wa[16 + hd] + x0.w * wa[24 + hd];
  float s1 = x1.x * wa[hd] + x1.y * wa[8 + hd] + x1.z * wa[16 + hd] + x1.w * wa[24 + hd];
  float d0 = x0.x * wa[32 + hd] + x0.y * wa[40 + hd] + x0.z * wa[48 + hd] + x0.w * wa[56 + hd];
  float d1 = x1.x * wa[32 + hd] + x1.y * wa[40 + hd] + x1.z * wa[48 + hd] + x1.w * wa[56 + hd];
  ssg[(size_t)n * 8 + hd] = s0; ssg[(size_t)(n + 1) * 8 + hd] = s1;
  sdg[(size_t)n * 8 + hd] = d0; sdg[(size_t)(n + 1) * 8 + hd] = d1;
  #pragma unroll 4
  for (int fi = 0; fi < 64; fi++) {
    int f = hd * 64 + fi;
    float w0 = W1[f], w1 = W1[512 + f], w2 = W1[1024 + f], w3 = W1[1536 + f];
    float h0 = x0.x * w0 + x0.y * w1 + x0.z * w2 + x0.w * w3;
    float h1 = x1.x * w0 + x1.y * w1 + x1.z * w2 + x1.w * w3;
    unsigned int pk = (unsigned int)f2bf(h0) | ((unsigned int)f2bf(h1) << 16);
    *(unsigned int*)(&hT[(size_t)f * NTP + n]) = pk;
  }
}

// Transposed GEMM with fused attention dots:
//   hT[f][n] = sum_k Wt[f][k] * X[n][k]   (bf16 out, fp32 acc)
__global__ __launch_bounds__(256) void k_bgemmT(
    const ushort_t* __restrict__ Wt, const ushort_t* __restrict__ X,
    const float* __restrict__ a_src, const float* __restrict__ a_dst,
    ushort_t* __restrict__ hT, float* __restrict__ ssg, float* __restrict__ sdg) {
  __shared__ ushort_t As[128 * 32];
  __shared__ ushort_t Bs[128 * 32];
  int tid = threadIdx.x;
  int w = tid >> 6, l = tid & 63;
  int row0 = blockIdx.y * 128;   // feature tile
  int col0 = blockIdx.x * 128;   // node tile
  int wr = w >> 1, wc = w & 1;

  f32x4 acc[4][4];
  #pragma unroll
  for (int i = 0; i < 4; i++)
    #pragma unroll
    for (int j = 0; j < 4; j++) acc[i][j] = (f32x4){0.f, 0.f, 0.f, 0.f};

  int srow = w * 32 + (l >> 2);
  int skcol = (l & 3) * 8;
  const ushort_t* Ag = Wt + (size_t)(row0 + srow) * FF + skcol;
  const ushort_t* Bg = X + (size_t)(col0 + srow) * FF + skcol;
  ushort_t* AsW = &As[w * 1024];
  ushort_t* BsW = &Bs[w * 1024];

  int m_l = l & 15, kq = (l >> 4) * 8;
  const ushort_t* ArdA = &As[(wr * 64 + m_l) * 32 + kq];
  const ushort_t* BrdB = &Bs[(wc * 64 + m_l) * 32 + kq];

  for (int k0 = 0; k0 < FF; k0 += 32) {
    gload_lds16(Ag + k0, AsW);
    gload_lds16(Ag + (size_t)16 * FF + k0, AsW + 512);
    gload_lds16(Bg + k0, BsW);
    gload_lds16(Bg + (size_t)16 * FF + k0, BsW + 512);
    __syncthreads();
    bf16x8 af[4], bfr[4];
    #pragma unroll
    for (int t = 0; t < 4; t++) {
      af[t]  = *(const bf16x8*)(ArdA + t * 16 * 32);
      bfr[t] = *(const bf16x8*)(BrdB + t * 16 * 32);
    }
    #pragma unroll
    for (int mt = 0; mt < 4; mt++)
      #pragma unroll
      for (int nt = 0; nt < 4; nt++)
        acc[mt][nt] = __builtin_amdgcn_mfma_f32_16x16x32_bf16(af[mt], bfr[nt], acc[mt][nt], 0, 0, 0);
    __syncthreads();
  }

  // epilogue: D[m=feature][n=node]; col=lane&15=node, row=quad*4+reg=feature
  int head = (row0 + wr * 64) >> 6;
  int rq = (l >> 4) * 4, cl = l & 15;
  float ds[4] = {0.f, 0.f, 0.f, 0.f}, dd[4] = {0.f, 0.f, 0.f, 0.f};
  #pragma unroll
  for (int mt = 0; mt < 4; mt++) {
    #pragma unroll
    for (int r = 0; r < 4; r++) {
      int f = row0 + wr * 64 + mt * 16 + rq + r;
      float a_s = a_src[f], a_d = a_dst[f];
      #pragma unroll
      for (int nt = 0; nt < 4; nt++) {
        float v = acc[mt][nt][r];
        ds[nt] += v * a_s;
        dd[nt] += v * a_d;
        int n = col0 + wc * 64 + nt * 16 + cl;
        hT[(size_t)f * NTP + n] = f2bf(v);
      }
    }
  }
  #pragma unroll
  for (int nt = 0; nt < 4; nt++) {
    ds[nt] += __shfl_xor(ds[nt], 16, 64); ds[nt] += __shfl_xor(ds[nt], 32, 64);
    dd[nt] += __shfl_xor(dd[nt], 16, 64); dd[nt] += __shfl_xor(dd[nt], 32, 64);
  }
  if (l < 16) {
    #pragma unroll
    for (int nt = 0; nt < 4; nt++) {
      int n = col0 + wc * 64 + nt * 16 + l;
      ssg[(size_t)n * 8 + head] = ds[nt];
      sdg[(size_t)n * 8 + head] = dd[nt];
    }
  }
}

// Unified fused GAT layer (one block per graph,head), Am aliased into P's LDS
// (occupancy: ~24.4 KB -> 6 blocks/CU). Edge data register-prefetched.
__global__ __launch_bounds__(256) void k_gatm(
    const ushort_t* __restrict__ hT,
    ushort_t* __restrict__ xout,         // layers 1,2
    ushort_t* __restrict__ cbf,          // layer 3 (pool fused)
    const float* __restrict__ ssg, const float* __restrict__ sdg,
    const ushort_t* __restrict__ epack, const float* __restrict__ eattr,
    const float* __restrict__ lattr, const float* __restrict__ gmm,
    const float* __restrict__ wdot_all, const float* __restrict__ bias,
    int layer, int self_loops) {
  int g = blockIdx.x, hd = blockIdx.y, tid = threadIdx.x;
  int w = tid >> 6, lane = tid & 63;

  __shared__ __align__(16) ushort_t ht[64 * 72];   // ht[c][s]
  __shared__ __align__(16) float P[50 * 68];       // scatter acc; Am aliases
  __shared__ float ssl[64], sdl[64];
  __shared__ float gsum[4 * 64];                   // pool partials
  ushort_t* Am = (ushort_t*)P;                     // bf16 [d][s], stride 72

  float wdot = wdot_all[layer * 8 + hd];
  float minEA = gmm[g * 2], maxEA = gmm[g * 2 + 1];
  float cmax = fmaxf(wdot * maxEA, wdot * minEA);
  int m_l = lane & 15, kq8 = (lane >> 4) * 8;

  // register-prefetch edge data (overlaps with staging latency)
  unsigned int pk0 = epack[g * EPG + tid];
  float ea0 = eattr[g * EPG + tid];
  unsigned int pk1 = 0; float ea1 = 0.f;
  if (tid < EPG - 256) { pk1 = epack[g * EPG + tid + 256]; ea1 = eattr[g * EPG + tid + 256]; }
  float la = (self_loops && tid < NP) ? lattr[g * NP + tid] : 0.f;

  // stage ht[c][0..63] from hT (cols >= 50 garbage-but-finite; Am cols are 0)
  for (int i = tid; i < 2048; i += 256) {
    int c = i >> 5, q = i & 31;
    *(unsigned int*)(&ht[c * 72 + q * 2]) =
        *(const unsigned int*)(&hT[(size_t)(hd * 64 + c) * NTP + g * NP + q * 2]);
  }
  if (tid < 64) {
    ssl[tid] = (tid < NP) ? ssg[(size_t)(g * NP + tid) * 8 + hd] : -1e30f;
    sdl[tid] = (tid < NP) ? sdg[(size_t)(g * NP + tid) * 8 + hd] : 0.f;
  }
  // zero P (850 uint4 = 13600 B)
  { uint4* z = (uint4*)P; uint4 zz = make_uint4(0u, 0u, 0u, 0u);
    for (int i = tid; i < 850; i += 256) z[i] = zz; }
  __syncthreads();

  // per-wave maxS over ssl
  float mv = ssl[lane];
  #pragma unroll
  for (int m = 32; m >= 1; m >>= 1) mv = fmaxf(mv, __shfl_xor(mv, m, 64));

  // edge scatter: p = exp(lr(al) - m_d), m_d = lr(maxS + sdl[d] + cmax) >= row max
  {
    int s = pk0 & 63, d = pk0 >> 6;
    float al = ssl[s] + sdl[d] + ea0 * wdot;
    al = al > 0.f ? al : 0.2f * al;
    float ub = mv + sdl[d] + cmax;
    ub = ub > 0.f ? ub : 0.2f * ub;
    atomicAdd(&P[d * 68 + s], __expf(al - ub));
  }
  if (tid < EPG - 256) {
    int s = pk1 & 63, d = pk1 >> 6;
    float al = ssl[s] + sdl[d] + ea1 * wdot;
    al = al > 0.f ? al : 0.2f * al;
    float ub = mv + sdl[d] + cmax;
    ub = ub > 0.f ? ub : 0.2f * ub;
    atomicAdd(&P[d * 68 + s], __expf(al - ub));
  }
  if (self_loops && tid < NP) {
    int d = tid;
    float al = ssl[d] + sdl[d] + la * wdot;
    al = al > 0.f ? al : 0.2f * al;
    float ub = mv + sdl[d] + cmax;
    ub = ub > 0.f ? ub : 0.2f * ub;
    atomicAdd(&P[d * 68 + d], __expf(al - ub));
  }
  __syncthreads();

  // normalize: read P -> regs, barrier, write bf16 Am into P's space
  {
    int d = tid >> 2, part = tid & 3;
    f32x4 v0, v1, v2, v3;
    float inv = 0.f;
    if (d < NP) {
      v0 = *(const f32x4*)(&P[d * 68 + part * 16 + 0]);
      v1 = *(const f32x4*)(&P[d * 68 + part * 16 + 4]);
      v2 = *(const f32x4*)(&P[d * 68 + part * 16 + 8]);
      v3 = *(const f32x4*)(&P[d * 68 + part * 16 + 12]);
      float sm = (v0[0] + v0[1] + v0[2] + v0[3]) + (v1[0] + v1[1] + v1[2] + v1[3])
               + (v2[0] + v2[1] + v2[2] + v2[3]) + (v3[0] + v3[1] + v3[2] + v3[3]);
      sm += __shfl_xor(sm, 1, 64);
      sm += __shfl_xor(sm, 2, 64);
      inv = 1.f / (sm + 1e-16f);
    }
    __syncthreads();   // all P reads complete before Am overwrites
    if (d < NP) {
      union { ushort_t u[8]; uint4 q; } p0, p1;
      p0.u[0] = f2bf(v0[0] * inv); p0.u[1] = f2bf(v0[1] * inv);
      p0.u[2] = f2bf(v0[2] * inv); p0.u[3] = f2bf(v0[3] * inv);
      p0.u[4] = f2bf(v1[0] * inv); p0.u[5] = f2bf(v1[1] * inv);
      p0.u[6] = f2bf(v1[2] * inv); p0.u[7] = f2bf(v1[3] * inv);
      p1.u[0] = f2bf(v2[0] * inv); p1.u[1] = f2bf(v2[1] * inv);
      p1.u[2] = f2bf(v2[2] * inv); p1.u[3] = f2bf(v2[3] * inv);
      p1.u[4] = f2bf(v3[0] * inv); p1.u[5] = f2bf(v3[1] * inv);
      p1.u[6] = f2bf(v3[2] * inv); p1.u[7] = f2bf(v3[3] * inv);
      *(uint4*)(&Am[d * 72 + part * 16]) = p0.q;
      *(uint4*)(&Am[d * 72 + part * 16 + 8]) = p1.q;
    } else {
      uint4 zz = make_uint4(0u, 0u, 0u, 0u);
      *(uint4*)(&Am[d * 72 + part * 16]) = zz;
      *(uint4*)(&Am[d * 72 + part * 16 + 8]) = zz;
    }
  }
  __syncthreads();

  // out MFMA: D[m=c][n=d] = ht @ Am^T; wave w owns d in [w*16, w*16+16)
  int d0 = w * 16;
  f32x4 acc[4];
  #pragma unroll
  for (int ct = 0; ct < 4; ct++) acc[ct] = (f32x4){0.f, 0.f, 0.f, 0.f};
  #pragma unroll
  for (int kc = 0; kc < 2; kc++) {
    int kb = kc * 32 + kq8;
    bf16x8 bfrag = *(const bf16x8*)(&Am[(d0 + m_l) * 72 + kb]);
    #pragma unroll
    for (int ct = 0; ct < 4; ct++) {
      bf16x8 afrag = *(const bf16x8*)(&ht[(ct * 16 + m_l) * 72 + kb]);
      acc[ct] = __builtin_amdgcn_mfma_f32_16x16x32_bf16(afrag, bfrag, acc[ct], 0, 0, 0);
    }
  }

  // bias + relu (C/D layout: row=(lane>>4)*4+reg = c, col=lane&15 = d)
  int d = d0 + m_l, rq = (lane >> 4) * 4;
  bool valid = (d < NP);
  float vv[4][4];
  #pragma unroll
  for (int ct = 0; ct < 4; ct++) {
    const float4 bv = *(const float4*)(&bias[hd * 64 + ct * 16 + rq]);
    vv[ct][0] = fmaxf(acc[ct][0] + bv.x, 0.f);
    vv[ct][1] = fmaxf(acc[ct][1] + bv.y, 0.f);
    vv[ct][2] = fmaxf(acc[ct][2] + bv.z, 0.f);
    vv[ct][3] = fmaxf(acc[ct][3] + bv.w, 0.f);
  }

  if (cbf == nullptr) {
    if (valid) {
      #pragma unroll
      for (int ct = 0; ct < 4; ct++) {
        union { ushort_t u[4]; uint2 v; } pk;
        pk.u[0] = f2bf(vv[ct][0]); pk.u[1] = f2bf(vv[ct][1]);
        pk.u[2] = f2bf(vv[ct][2]); pk.u[3] = f2bf(vv[ct][3]);
        *(uint2*)(&xout[(size_t)(g * NP + d) * FF + hd * 64 + ct * 16 + rq]) = pk.v;
      }
    }
  } else {
    // fused pool: agent rows d<5 -> combined[:512]; mean over d -> combined[512:]
    #pragma unroll
    for (int ct = 0; ct < 4; ct++) {
      #pragma unroll
      for (int r = 0; r < 4; r++) {
        float t = valid ? vv[ct][r] : 0.f;
        t += __shfl_xor(t, 1, 64); t += __shfl_xor(t, 2, 64);
        t += __shfl_xor(t, 4, 64); t += __shfl_xor(t, 8, 64);
        if (m_l == 0) gsum[w * 64 + ct * 16 + rq + r] = t;
      }
    }
    if (w == 0 && m_l < 5) {
      #pragma unroll
      for (int ct = 0; ct < 4; ct++) {
        union { ushort_t u[4]; uint2 v; } pk;
        pk.u[0] = f2bf(vv[ct][0]); pk.u[1] = f2bf(vv[ct][1]);
        pk.u[2] = f2bf(vv[ct][2]); pk.u[3] = f2bf(vv[ct][3]);
        *(uint2*)(&cbf[(size_t)(g * 5 + d) * GRUIN + hd * 64 + ct * 16 + rq]) = pk.v;
      }
    }
    __syncthreads();
    if (tid < 64) {
      float mean = (gsum[tid] + gsum[64 + tid] + gsum[128 + tid] + gsum[192 + tid]) * (1.f / NP);
      ushort_t mb = f2bf(mean);
      #pragma unroll
      for (int t = 0; t < 5; t++)
        cbf[(size_t)(g * 5 + t) * GRUIN + 512 + hd * 64 + tid] = mb;
    }
  }
}

// generic bf16 MFMA GEMM (row-major C fp32) — used for the GRU input GEMM
__global__ __launch_bounds__(256) void k_bgemm(
    const ushort_t* __restrict__ A, const ushort_t* __restrict__ Bt,
    const float* __restrict__ bias, float* __restrict__ C,
    int M, int N, int K) {
  __shared__ ushort_t As[128 * 32];
  __shared__ ushort_t Bs[128 * 32];
  int tid = threadIdx.x;
  int w = tid >> 6, l = tid & 63;
  int row0 = blockIdx.y * 128, col0 = blockIdx.x * 128;
  int wr = w >> 1, wc = w & 1;

  f32x4 acc[4][4];
  #pragma unroll
  for (int i = 0; i < 4; i++)
    #pragma unroll
    for (int j = 0; j < 4; j++) acc[i][j] = (f32x4){0.f, 0.f, 0.f, 0.f};

  int srow = w * 32 + (l >> 2);
  int skcol = (l & 3) * 8;
  const ushort_t* Ag = A + (size_t)(row0 + srow) * K + skcol;
  const ushort_t* Bg = Bt + (size_t)(col0 + srow) * K + skcol;
  ushort_t* AsW = &As[w * 1024];
  ushort_t* BsW = &Bs[w * 1024];

  int m_l = l & 15, kq = (l >> 4) * 8;
  const ushort_t* ArdA = &As[(wr * 64 + m_l) * 32 + kq];
  const ushort_t* BrdB = &Bs[(wc * 64 + m_l) * 32 + kq];

  for (int k0 = 0; k0 < K; k0 += 32) {
    gload_lds16(Ag + k0, AsW);
    gload_lds16(Ag + (size_t)16 * K + k0, AsW + 512);
    gload_lds16(Bg + k0, BsW);
    gload_lds16(Bg + (size_t)16 * K + k0, BsW + 512);
    __syncthreads();
    bf16x8 af[4], bfr[4];
    #pragma unroll
    for (int t = 0; t < 4; t++) {
      af[t]  = *(const bf16x8*)(ArdA + t * 16 * 32);
      bfr[t] = *(const bf16x8*)(BrdB + t * 16 * 32);
    }
    #pragma unroll
    for (int mt = 0; mt < 4; mt++)
      #pragma unroll
      for (int nt = 0; nt < 4; nt++)
        acc[mt][nt] = __builtin_amdgcn_mfma_f32_16x16x32_bf16(af[mt], bfr[nt], acc[mt][nt], 0, 0, 0);
    __syncthreads();
  }

  int cl = l & 15, rq = (l >> 4) * 4;
  #pragma unroll
  for (int mt = 0; mt < 4; mt++) {
    #pragma unroll
    for (int nt = 0; nt < 4; nt++) {
      int col = col0 + wc * 64 + nt * 16 + cl;
      float bv = bias ? bias[col] : 0.f;
      #pragma unroll
      for (int r = 0; r < 4; r++) {
        int row = row0 + wr * 64 + mt * 16 + rq + r;
        C[(size_t)row * N + col] = acc[mt][nt][r] + bv;
      }
    }
  }
}

// GRU: one block per batch element, 5 sequential steps. gi_all already has bih.
__global__ void k_gru(const float* __restrict__ gi_all, const float* __restrict__ h0,
                      const float* __restrict__ Whh, const float* __restrict__ bhh,
                      float* __restrict__ gru_out, float* __restrict__ hlast) {
  int b = blockIdx.x, tid = threadIdx.x;   // 384 threads
  __shared__ float hl[GRUH];
  __shared__ float ghb[384];
  if (tid < GRUH) hl[tid] = h0[b * GRUH + tid];
  for (int t = 0; t < 5; t++) {
    __syncthreads();
    float acc = bhh[tid];
    for (int k = 0; k < GRUH; k++) acc += hl[k] * Whh[k * 384 + tid];
    ghb[tid] = acc;
    __syncthreads();
    if (tid < GRUH) {
      const float* gi = gi_all + (size_t)(b * 5 + t) * 384;
      float r = 1.f / (1.f + expf(-(gi[tid] + ghb[tid])));
      float z = 1.f / (1.f + expf(-(gi[128 + tid] + ghb[128 + tid])));
      float nn = tanhf(gi[256 + tid] + r * ghb[256 + tid]);
      float hn = (1.f - z) * nn + z * hl[tid];
      gru_out[(size_t)(b * 5 + t) * GRUH + tid] = hn;
      hl[tid] = hn;
    }
  }
  __syncthreads();
  if (tid < GRUH) hlast[b * GRUH + tid] = hl[tid];
}

// fc1(relu) + fc2 + action_std, one block (64 thr) per (b,t) row
__global__ void k_fc(const float* __restrict__ gru_out, const float* __restrict__ fc1W,
                     const float* __restrict__ fc1b, const float* __restrict__ fc2W,
                     const float* __restrict__ fc2b, const float* __restrict__ log_std,
                     float* __restrict__ dout) {
  int row = blockIdx.x, tid = threadIdx.x;   // 64 threads
  __shared__ float gbuf[GRUH];
  __shared__ float f1[64];
  gbuf[tid] = gru_out[(size_t)row * GRUH + tid];
  gbuf[tid + 64] = gru_out[(size_t)row * GRUH + 64 + tid];
  __syncthreads();
  float acc = fc1b[tid];
  for (int k = 0; k < GRUH; k++) acc += gbuf[k] * fc1W[k * 64 + tid];
  f1[tid] = fmaxf(acc, 0.f);
  __syncthreads();
  if (tid < 3) {
    float o = fc2b[tid];
    for (int j = 0; j < 64; j++) o += f1[j] * fc2W[j * 3 + tid];
    dout[row * 3 + tid] = o;
    float ls = log_std[tid];
    ls = fminf(fmaxf(ls, -20.f), 2.f);
    dout[7680 + row * 3 + tid] = expf(ls);
  }
}

extern "C" void kernel_launch(void* const* d_in, const int* in_sizes, int n_in,
                              void* d_out, int out_size, void* d_ws, size_t ws_size,
                              hipStream_t stream) {
  const float* x      = (const float*)d_in[0];
  const int*   ei     = (const int*)d_in[1];
  const float* eattr  = (const float*)d_in[2];
  const float* hstate = (const float*)d_in[3];
  const float* W1  = (const float*)d_in[4];
  const float* as1 = (const float*)d_in[5];
  const float* ad1 = (const float*)d_in[6];
  const float* We1 = (const float*)d_in[7];
  const float* ae1 = (const float*)d_in[8];
  const float* b1  = (const float*)d_in[9];
  const float* W2  = (const float*)d_in[10];
  const float* as2 = (const float*)d_in[11];
  const float* ad2 = (const float*)d_in[12];
  const float* We2 = (const float*)d_in[13];
  const float* ae2 = (const float*)d_in[14];
  const float* b2  = (const float*)d_in[15];
  const float* W3  = (const float*)d_in[16];
  const float* as3 = (const float*)d_in[17];
  const float* ad3 = (const float*)d_in[18];
  const float* We3 = (const float*)d_in[19];
  const float* ae3 = (const float*)d_in[20];
  const float* b3  = (const float*)d_in[21];
  const float* Wih = (const float*)d_in[22];
  const float* Whh = (const float*)d_in[23];
  const float* bih = (const float*)d_in[24];
  const float* bhh = (const float*)d_in[25];
  const float* fc1W = (const float*)d_in[26];
  const float* fc1b = (const float*)d_in[27];
  const float* fc2W = (const float*)d_in[28];
  const float* fc2b = (const float*)d_in[29];
  const float* lstd = (const float*)d_in[30];

  float* ws = (float*)d_ws;
  ushort_t* xbf = (ushort_t*)ws;                     // 13,107,200 us
  ushort_t* hT  = (ushort_t*)(ws + 6553600);         // 512*25664 us
  float* p = ws + 6553600 + 6569984;
  float* ssg   = p;           p += 204800;
  float* sdg   = p;           p += 204800;
  float* lattr = p;           p += 25600;
  float* gmm   = p;           p += 1024;
  float* wdot  = p;           p += 32;
  float* wa    = p;           p += 64;
  ushort_t* epack = (ushort_t*)p; p += 102400;   // 204800 ushorts
  ushort_t* w2t  = (ushort_t*)p;  p += 131072;   // 262144 us
  ushort_t* w3t  = (ushort_t*)p;  p += 131072;
  ushort_t* wiht = (ushort_t*)p;  p += 196608;   // 393216 us
  ushort_t* cbf  = (ushort_t*)p;  p += 1310720;  // 2,621,440 us
  float* gi_all  = p;         p += 983040;       // [2560][384]
  float* gru_out = p;         p += 327680;
  float* dout = (float*)d_out;

  k_wedot<<<4, 512, 0, stream>>>(We1, ae1, We2, ae2, We3, ae3, W1, as1, ad1, wdot, wa);
  k_lattr<<<BB, 256, 0, stream>>>(ei, eattr, lattr, gmm, epack);
  k_cvt_t<<<dim3(16, 16), 256, 0, stream>>>(W2, w2t, FF, FF);
  k_cvt_t<<<dim3(16, 16), 256, 0, stream>>>(W3, w3t, FF, FF);
  k_cvt_t<<<dim3(12, 32), 256, 0, stream>>>(Wih, wiht, GRUIN, 384);

  // layer 1: h1T = (x@W1)^T + dots (rank-4); gat -> xbf
  k_h1T<<<dim3(50, 8), 256, 0, stream>>>(x, W1, wa, hT, ssg, sdg);
  k_gatm<<<dim3(BB, HH), 256, 0, stream>>>(hT, xbf, nullptr, ssg, sdg, epack, eattr,
                                           lattr, gmm, wdot, b1, 0, 0);
  // layer 2: hT = W2t @ x1^T (+ fused dots); gat -> xbf
  k_bgemmT<<<dim3(200, 4), 256, 0, stream>>>(w2t, xbf, as2, ad2, hT, ssg, sdg);
  k_gatm<<<dim3(BB, HH), 256, 0, stream>>>(hT, xbf, nullptr, ssg, sdg, epack, eattr,
                                           lattr, gmm, wdot, b2, 1, 1);
  // layer 3: gat with fused agent-gather + mean-pool -> cbf
  k_bgemmT<<<dim3(200, 4), 256, 0, stream>>>(w3t, xbf, as3, ad3, hT, ssg, sdg);
  k_gatm<<<dim3(BB, HH), 256, 0, stream>>>(hT, nullptr, cbf, ssg, sdg, epack, eattr,
                                           lattr, gmm, wdot, b3, 2, 1);

  // GRU input GEMM (adds bih)
  k_bgemm<<<dim3(3, 20), 256, 0, stream>>>(cbf, wiht, bih, gi_all, 2560, 384, GRUIN);

  // GRU scan + heads
  k_gru<<<BB, 384, 0, stream>>>(gi_all, hstate, Whh, bhh, gru_out, dout + 15360);
  k_fc<<<2560, 64, 0, stream>>>(gru_out, fc1W, fc1b, fc2W, fc2b, lstd, dout);
}

// Round 9
// 304.600 us; speedup vs baseline: 1.2450x; 1.1874x over previous
//
#include <hip/hip_runtime.h>
#include <math.h>

#define NN 25600      // total nodes
#define BB 512        // graphs
#define NP 50         // nodes per graph
#define EPG 400       // edges per graph
#define EE 204800     // total edges
#define HH 8
#define FF 512
#define GRUH 128
#define GRUIN 1024

typedef unsigned short ushort_t;
typedef __attribute__((ext_vector_type(8))) short bf16x8;
typedef __attribute__((ext_vector_type(4))) float f32x4;

__device__ __forceinline__ float wave_reduce_sum(float v) {
  #pragma unroll
  for (int m = 32; m >= 1; m >>= 1) v += __shfl_xor(v, m, 64);
  return v;
}

__device__ __forceinline__ ushort_t f2bf(float x) {
  union { float f; unsigned int u; } v; v.f = x;
  unsigned int r = v.u + 0x7fffu + ((v.u >> 16) & 1u);   // RNE
  return (ushort_t)(r >> 16);
}

__device__ __forceinline__ float bf2f(ushort_t u) {
  union { unsigned int u; float f; } v; v.u = ((unsigned int)u) << 16;
  return v.f;
}

__device__ __forceinline__ void gload_lds16(const ushort_t* g, ushort_t* l) {
  __builtin_amdgcn_global_load_lds(
      (const __attribute__((address_space(1))) void*)g,
      (__attribute__((address_space(3))) void*)l, 16, 0, 0);
}

// Merged prologue, 1409 blocks:
//  [0,256)   cvt W2 -> w2t[f][k] bf16      [256,512) cvt W3
//  [512,896) cvt Wih (K=1024,N=384)        [896,1408) per-graph CSR+lattr
//  1408      we_dot for 3 layers x 8 heads
__global__ __launch_bounds__(256) void k_pre(
    const float* __restrict__ W2, const float* __restrict__ W3,
    const float* __restrict__ Wih,
    ushort_t* __restrict__ w2t, ushort_t* __restrict__ w3t, ushort_t* __restrict__ wiht,
    const int* __restrict__ ei, const float* __restrict__ eattr,
    int* __restrict__ rowp, ushort_t* __restrict__ esrc, float* __restrict__ eea,
    float* __restrict__ lattr,
    const float* __restrict__ We1, const float* __restrict__ ae1,
    const float* __restrict__ We2, const float* __restrict__ ae2,
    const float* __restrict__ We3, const float* __restrict__ ae3,
    float* __restrict__ wdot) {
  int b = blockIdx.x, tid = threadIdx.x;
  __shared__ float t[32][33];
  __shared__ int cnt[NP];
  __shared__ float esum[NP];
  __shared__ int rp[NP + 1];
  __shared__ int cur[NP];

  if (b < 896) {
    const float* W; ushort_t* Wt; int K, N, n0, k0;
    if (b < 256)      { W = W2;  Wt = w2t;  K = 512;  N = 512; n0 = (b & 15) * 32;        k0 = (b >> 4) * 32; }
    else if (b < 512) { W = W3;  Wt = w3t;  K = 512;  N = 512; n0 = ((b - 256) & 15) * 32; k0 = ((b - 256) >> 4) * 32; }
    else              { W = Wih; Wt = wiht; K = 1024; N = 384; n0 = ((b - 512) % 12) * 32; k0 = ((b - 512) / 12) * 32; }
    int tx = tid & 31, ty = tid >> 5;
    #pragma unroll
    for (int i = 0; i < 4; i++)
      t[ty + i * 8][tx] = W[(size_t)(k0 + ty + i * 8) * N + n0 + tx];
    __syncthreads();
    #pragma unroll
    for (int i = 0; i < 4; i++)
      Wt[(size_t)(n0 + ty + i * 8) * K + k0 + tx] = f2bf(t[tx][ty + i * 8]);
  } else if (b < 1408) {
    int g = b - 896;
    if (tid < NP) { cnt[tid] = 0; esum[tid] = 0.f; }
    __syncthreads();
    for (int e = tid; e < EPG; e += 256) {
      int ge = g * EPG + e;
      int dl = ei[EE + ge] - g * NP;
      atomicAdd(&cnt[dl], 1);
      atomicAdd(&esum[dl], eattr[ge]);
    }
    __syncthreads();
    if (tid == 0) {
      int s = 0;
      for (int i = 0; i < NP; i++) { rp[i] = s; cur[i] = s; s += cnt[i]; }
      rp[NP] = s;
    }
    __syncthreads();
    if (tid <= NP) rowp[g * 64 + tid] = rp[tid];
    if (tid < NP) lattr[g * NP + tid] = esum[tid] / (float)max(cnt[tid], 1);
    for (int e = tid; e < EPG; e += 256) {
      int ge = g * EPG + e;
      int sl = ei[ge] - g * NP;
      int dl = ei[EE + ge] - g * NP;
      int pos = atomicAdd(&cur[dl], 1);
      esrc[g * EPG + pos] = (ushort_t)sl;
      eea[g * EPG + pos] = eattr[ge];
    }
  } else {
    int w = tid >> 6, lane = tid & 63;
    for (int i = 0; i < 6; i++) {
      int idx = w + 4 * i;              // 24 (layer,head) pairs
      int l = idx >> 3, h = idx & 7;
      const float* We = l == 0 ? We1 : (l == 1 ? We2 : We3);
      const float* ae = l == 0 ? ae1 : (l == 1 ? ae2 : ae3);
      float v = wave_reduce_sum(We[h * 64 + lane] * ae[h * 64 + lane]);
      if (lane == 0) wdot[l * 8 + h] = v;
    }
  }
}

// Fully-fused GAT layer: one block = (graph g, head-half). 4 waves = 4 heads.
// GEMM (h = x@W, MFMA K=512, or VALU rank-4 for layer 1) -> h to LDS (bf16,
// xor-swizzled) + in-register dots -> per-lane CSR softmax (true max, bf16 Am
// accumulate) -> A@h MFMA -> bias+relu -> x out (L1,L2) or fused pool (L3).
// NOTE: input (Xbf) and output (xout) must be DISTINCT buffers (no in-place).
__global__ __launch_bounds__(256) void k_layer(
    const ushort_t* __restrict__ Xbf,   // layers 2,3 input [NN+64][512] bf16
    const float* __restrict__ x4,       // layer 1 input [NN][4]
    const float* __restrict__ W1,       // layer 1 [4][512]
    const ushort_t* __restrict__ Wt,    // layers 2,3 [512][512] bf16 (W^T)
    const float* __restrict__ a_src, const float* __restrict__ a_dst,
    ushort_t* __restrict__ xout,        // layers 1,2
    ushort_t* __restrict__ cbf,         // layer 3
    const int* __restrict__ rowp, const ushort_t* __restrict__ esrc,
    const float* __restrict__ eea, const float* __restrict__ lattr,
    const float* __restrict__ wdot_all, const float* __restrict__ bias,
    int layer, int self_loops) {
  int g = blockIdx.x, half = blockIdx.y, tid = threadIdx.x;
  int w = tid >> 6, l = tid & 63;
  int fbase = half * 256;
  int head = half * 4 + w;
  int m_l = l & 15, quad = l >> 4, rq = quad * 4, kq8 = quad * 8;

  __shared__ __align__(16) ushort_t hS[256 * 64];   // h[fl][s^((fl&3)<<3)]
  __shared__ __align__(16) ushort_t U[13696];       // staging / W1s+xs / Am
  __shared__ ushort_t esrcS[400];
  __shared__ float eeaS[400];
  __shared__ int rowpS[51];
  __shared__ float lattrS[50];
  __shared__ float sslS[256], sdlS[256];

  // stage edge/CSR data
  for (int i = tid; i < 400; i += 256) { esrcS[i] = esrc[g * EPG + i]; eeaS[i] = eea[g * EPG + i]; }
  if (tid <= NP) rowpS[tid] = rowp[g * 64 + tid];
  if (tid < NP) lattrS[tid] = lattr[g * NP + tid];

  f32x4 acc[4][4];
  #pragma unroll
  for (int i = 0; i < 4; i++)
    #pragma unroll
    for (int j = 0; j < 4; j++) acc[i][j] = (f32x4){0.f, 0.f, 0.f, 0.f};

  if (layer == 0) {
    float* W1s = (float*)U;            // [4][256]
    float* xs = (float*)U + 1024;      // [64][4]
    for (int i = tid; i < 1024; i += 256) {
      int k = i >> 8, j = i & 255;
      W1s[i] = W1[k * 512 + fbase + j];
    }
    if (tid < NP) *(float4*)(&xs[tid * 4]) = *(const float4*)(&x4[(size_t)(g * NP + tid) * 4]);
    else if (tid < 64) *(float4*)(&xs[tid * 4]) = make_float4(0.f, 0.f, 0.f, 0.f);
    __syncthreads();
    float xr[4][4];
    #pragma unroll
    for (int nt = 0; nt < 4; nt++)
      #pragma unroll
      for (int k = 0; k < 4; k++) xr[nt][k] = xs[(nt * 16 + m_l) * 4 + k];
    #pragma unroll
    for (int mt = 0; mt < 4; mt++) {
      float wv[4][4];
      #pragma unroll
      for (int r = 0; r < 4; r++)
        #pragma unroll
        for (int k = 0; k < 4; k++) wv[r][k] = W1s[k * 256 + w * 64 + mt * 16 + rq + r];
      #pragma unroll
      for (int nt = 0; nt < 4; nt++)
        #pragma unroll
        for (int r = 0; r < 4; r++)
          acc[mt][nt][r] = xr[nt][0] * wv[r][0] + xr[nt][1] * wv[r][1]
                         + xr[nt][2] * wv[r][2] + xr[nt][3] * wv[r][3];
    }
  } else {
    ushort_t* As = U;                  // [256][32]
    ushort_t* Bs = U + 8192;           // [64][32]
    const ushort_t* Ag = Wt + (size_t)(fbase + w * 64 + (l >> 2)) * FF + (l & 3) * 8;
    const ushort_t* Bg = Xbf + (size_t)(g * NP + w * 16 + (l >> 2)) * FF + (l & 3) * 8;
    ushort_t* AsW = As + w * 2048;
    ushort_t* BsW = Bs + w * 512;
    for (int k0 = 0; k0 < FF; k0 += 32) {
      #pragma unroll
      for (int j = 0; j < 4; j++)
        gload_lds16(Ag + (size_t)j * 16 * FF + k0, AsW + j * 512);
      gload_lds16(Bg + k0, BsW);
      __syncthreads();
      bf16x8 af[4], bfr[4];
      #pragma unroll
      for (int mt = 0; mt < 4; mt++)
        af[mt] = *(const bf16x8*)(As + (w * 64 + mt * 16 + m_l) * 32 + kq8);
      #pragma unroll
      for (int nt = 0; nt < 4; nt++)
        bfr[nt] = *(const bf16x8*)(Bs + (nt * 16 + m_l) * 32 + kq8);
      #pragma unroll
      for (int mt = 0; mt < 4; mt++)
        #pragma unroll
        for (int nt = 0; nt < 4; nt++)
          acc[mt][nt] = __builtin_amdgcn_mfma_f32_16x16x32_bf16(af[mt], bfr[nt], acc[mt][nt], 0, 0, 0);
      __syncthreads();
    }
  }

  // h -> LDS (bf16, swizzled) + dots in-register (D: m=f -> quad*4+r, n=s -> m_l)
  float ds[4] = {0.f, 0.f, 0.f, 0.f}, dd[4] = {0.f, 0.f, 0.f, 0.f};
  #pragma unroll
  for (int mt = 0; mt < 4; mt++) {
    float a_s[4], a_d[4];
    #pragma unroll
    for (int r = 0; r < 4; r++) {
      int fg = fbase + w * 64 + mt * 16 + rq + r;
      a_s[r] = a_src[fg]; a_d[r] = a_dst[fg];
    }
    #pragma unroll
    for (int nt = 0; nt < 4; nt++) {
      int s = nt * 16 + m_l;
      #pragma unroll
      for (int r = 0; r < 4; r++) {
        float v = acc[mt][nt][r];
        ds[nt] += v * a_s[r];
        dd[nt] += v * a_d[r];
        int fl = w * 64 + mt * 16 + rq + r;
        hS[fl * 64 + (s ^ ((fl & 3) << 3))] = f2bf(v);
      }
    }
  }
  #pragma unroll
  for (int nt = 0; nt < 4; nt++) {
    ds[nt] += __shfl_xor(ds[nt], 16, 64); ds[nt] += __shfl_xor(ds[nt], 32, 64);
    dd[nt] += __shfl_xor(dd[nt], 16, 64); dd[nt] += __shfl_xor(dd[nt], 32, 64);
  }
  if (l < 16) {
    #pragma unroll
    for (int nt = 0; nt < 4; nt++) {
      sslS[w * 64 + nt * 16 + l] = ds[nt];
      sdlS[w * 64 + nt * 16 + l] = dd[nt];
    }
  }
  __syncthreads();

  // zero U (Am region): head w slot = U + w*3200, rows d stride 64 (swizzled)
  { uint4* z = (uint4*)U; for (int i = tid; i < 1712; i += 256) z[i] = make_uint4(0u, 0u, 0u, 0u); }
  __syncthreads();

  ushort_t* AmW = U + w * 3200;
  float wdot = wdot_all[layer * 8 + head];
  if (l < NP) {
    int d = l;
    int e0 = rowpS[d], e1 = rowpS[d + 1];
    float sd = sdlS[w * 64 + d];
    float m = -1e30f;
    for (int e = e0; e < e1; e++) {
      float al = sslS[w * 64 + esrcS[e]] + sd + eeaS[e] * wdot;
      al = al > 0.f ? al : 0.2f * al;
      m = fmaxf(m, al);
    }
    float al_loop = 0.f;
    if (self_loops) {
      al_loop = sslS[w * 64 + d] + sd + lattrS[d] * wdot;
      al_loop = al_loop > 0.f ? al_loop : 0.2f * al_loop;
      m = fmaxf(m, al_loop);
    }
    if (e1 > e0 || self_loops) {
      float denom = 0.f;
      for (int e = e0; e < e1; e++) {
        float al = sslS[w * 64 + esrcS[e]] + sd + eeaS[e] * wdot;
        al = al > 0.f ? al : 0.2f * al;
        float p = __expf(al - m);
        denom += p;
        int sp = esrcS[e] ^ ((d & 3) << 3);
        float prev = bf2f(AmW[d * 64 + sp]);
        AmW[d * 64 + sp] = f2bf(prev + p);
      }
      if (self_loops) {
        float p = __expf(al_loop - m);
        denom += p;
        int sp = d ^ ((d & 3) << 3);
        float prev = bf2f(AmW[d * 64 + sp]);
        AmW[d * 64 + sp] = f2bf(prev + p);
      }
      float inv = 1.f / (denom + 1e-16f);
      #pragma unroll
      for (int c = 0; c < 8; c++) {
        union { ushort_t u[8]; uint4 q; } pk;
        pk.q = *(uint4*)(AmW + d * 64 + c * 8);
        #pragma unroll
        for (int j = 0; j < 8; j++) pk.u[j] = f2bf(bf2f(pk.u[j]) * inv);
        *(uint4*)(AmW + d * 64 + c * 8) = pk.q;
      }
    }
  }
  __syncthreads();

  // out MFMA: D[m=f_local][n=d] = h @ Am^T (k = s, 64)
  f32x4 oacc[4][4];
  #pragma unroll
  for (int i = 0; i < 4; i++)
    #pragma unroll
    for (int j = 0; j < 4; j++) oacc[i][j] = (f32x4){0.f, 0.f, 0.f, 0.f};
  #pragma unroll
  for (int kc = 0; kc < 2; kc++) {
    int kb = kc * 32 + kq8;
    bf16x8 bfr2[4];
    #pragma unroll
    for (int nt = 0; nt < 4; nt++) {
      int d = nt * 16 + m_l;
      bfr2[nt] = *(const bf16x8*)(AmW + d * 64 + (kb ^ ((d & 3) << 3)));
    }
    #pragma unroll
    for (int mt = 0; mt < 4; mt++) {
      int fl = w * 64 + mt * 16 + m_l;
      bf16x8 afr = *(const bf16x8*)(hS + fl * 64 + (kb ^ ((fl & 3) << 3)));
      #pragma unroll
      for (int nt = 0; nt < 4; nt++)
        oacc[mt][nt] = __builtin_amdgcn_mfma_f32_16x16x32_bf16(afr, bfr2[nt], oacc[mt][nt], 0, 0, 0);
    }
  }

  // bias + relu; D: n=d -> m_l per nt, m=f -> quad*4+r per mt
  float vv[4][4][4];   // [mt][nt][r]
  #pragma unroll
  for (int mt = 0; mt < 4; mt++) {
    const float4 bv = *(const float4*)(&bias[fbase + w * 64 + mt * 16 + rq]);
    #pragma unroll
    for (int nt = 0; nt < 4; nt++) {
      vv[mt][nt][0] = fmaxf(oacc[mt][nt][0] + bv.x, 0.f);
      vv[mt][nt][1] = fmaxf(oacc[mt][nt][1] + bv.y, 0.f);
      vv[mt][nt][2] = fmaxf(oacc[mt][nt][2] + bv.z, 0.f);
      vv[mt][nt][3] = fmaxf(oacc[mt][nt][3] + bv.w, 0.f);
    }
  }

  if (cbf == nullptr) {
    #pragma unroll
    for (int nt = 0; nt < 4; nt++) {
      int d = nt * 16 + m_l;
      if (d < NP) {
        #pragma unroll
        for (int mt = 0; mt < 4; mt++) {
          union { ushort_t u[4]; uint2 v; } pk;
          #pragma unroll
          for (int r = 0; r < 4; r++) pk.u[r] = f2bf(vv[mt][nt][r]);
          *(uint2*)(&xout[(size_t)(g * NP + d) * FF + fbase + w * 64 + mt * 16 + rq]) = pk.v;
        }
      }
    }
  } else {
    // fused pool (layer 3): agents d<5; mean over d per f (wave-local)
    #pragma unroll
    for (int mt = 0; mt < 4; mt++) {
      float msum[4];
      #pragma unroll
      for (int r = 0; r < 4; r++) {
        float t = 0.f;
        #pragma unroll
        for (int nt = 0; nt < 4; nt++) {
          int d = nt * 16 + m_l;
          t += (d < NP) ? vv[mt][nt][r] : 0.f;
        }
        t += __shfl_xor(t, 1, 64); t += __shfl_xor(t, 2, 64);
        t += __shfl_xor(t, 4, 64); t += __shfl_xor(t, 8, 64);
        msum[r] = t * (1.f / NP);
      }
      if (m_l == 0) {
        union { ushort_t u[4]; uint2 v; } pk;
        #pragma unroll
        for (int r = 0; r < 4; r++) pk.u[r] = f2bf(msum[r]);
        #pragma unroll
        for (int t5 = 0; t5 < 5; t5++)
          *(uint2*)(&cbf[(size_t)(g * 5 + t5) * GRUIN + 512 + fbase + w * 64 + mt * 16 + rq]) = pk.v;
      }
      if (m_l < 5) {   // agents: d = m_l (nt = 0)
        union { ushort_t u[4]; uint2 v; } pk;
        #pragma unroll
        for (int r = 0; r < 4; r++) pk.u[r] = f2bf(vv[mt][0][r]);
        *(uint2*)(&cbf[(size_t)(g * 5 + m_l) * GRUIN + fbase + w * 64 + mt * 16 + rq]) = pk.v;
      }
    }
  }
}

// generic bf16 MFMA GEMM (row-major C fp32) — GRU input GEMM
__global__ __launch_bounds__(256) void k_bgemm(
    const ushort_t* __restrict__ A, const ushort_t* __restrict__ Bt,
    const float* __restrict__ bias, float* __restrict__ C,
    int M, int N, int K) {
  __shared__ ushort_t As[128 * 32];
  __shared__ ushort_t Bs[128 * 32];
  int tid = threadIdx.x;
  int w = tid >> 6, l = tid & 63;
  int row0 = blockIdx.y * 128, col0 = blockIdx.x * 128;
  int wr = w >> 1, wc = w & 1;

  f32x4 acc[4][4];
  #pragma unroll
  for (int i = 0; i < 4; i++)
    #pragma unroll
    for (int j = 0; j < 4; j++) acc[i][j] = (f32x4){0.f, 0.f, 0.f, 0.f};

  int srow = w * 32 + (l >> 2);
  int skcol = (l & 3) * 8;
  const ushort_t* Ag = A + (size_t)(row0 + srow) * K + skcol;
  const ushort_t* Bg = Bt + (size_t)(col0 + srow) * K + skcol;
  ushort_t* AsW = &As[w * 1024];
  ushort_t* BsW = &Bs[w * 1024];

  int m_l = l & 15, kq = (l >> 4) * 8;
  const ushort_t* ArdA = &As[(wr * 64 + m_l) * 32 + kq];
  const ushort_t* BrdB = &Bs[(wc * 64 + m_l) * 32 + kq];

  for (int k0 = 0; k0 < K; k0 += 32) {
    gload_lds16(Ag + k0, AsW);
    gload_lds16(Ag + (size_t)16 * K + k0, AsW + 512);
    gload_lds16(Bg + k0, BsW);
    gload_lds16(Bg + (size_t)16 * K + k0, BsW + 512);
    __syncthreads();
    bf16x8 af[4], bfr[4];
    #pragma unroll
    for (int t = 0; t < 4; t++) {
      af[t]  = *(const bf16x8*)(ArdA + t * 16 * 32);
      bfr[t] = *(const bf16x8*)(BrdB + t * 16 * 32);
    }
    #pragma unroll
    for (int mt = 0; mt < 4; mt++)
      #pragma unroll
      for (int nt = 0; nt < 4; nt++)
        acc[mt][nt] = __builtin_amdgcn_mfma_f32_16x16x32_bf16(af[mt], bfr[nt], acc[mt][nt], 0, 0, 0);
    __syncthreads();
  }

  int cl = l & 15, rq = (l >> 4) * 4;
  #pragma unroll
  for (int mt = 0; mt < 4; mt++) {
    #pragma unroll
    for (int nt = 0; nt < 4; nt++) {
      int col = col0 + wc * 64 + nt * 16 + cl;
      float bv = bias ? bias[col] : 0.f;
      #pragma unroll
      for (int r = 0; r < 4; r++) {
        int row = row0 + wr * 64 + mt * 16 + rq + r;
        C[(size_t)row * N + col] = acc[mt][nt][r] + bv;
      }
    }
  }
}

// GRU (5 steps) + fc1(relu) + fc2 + action_std, one block per batch element
__global__ void k_grufc(const float* __restrict__ gi_all, const float* __restrict__ h0,
                        const float* __restrict__ Whh, const float* __restrict__ bhh,
                        const float* __restrict__ fc1W, const float* __restrict__ fc1b,
                        const float* __restrict__ fc2W, const float* __restrict__ fc2b,
                        const float* __restrict__ log_std, float* __restrict__ dout) {
  int b = blockIdx.x, tid = threadIdx.x;   // 384 threads
  __shared__ float hl[GRUH];
  __shared__ float ghb[384];
  __shared__ float go[5 * GRUH];
  __shared__ float f1[5 * 64];
  if (tid < GRUH) hl[tid] = h0[b * GRUH + tid];
  for (int t = 0; t < 5; t++) {
    __syncthreads();
    float acc = bhh[tid];
    for (int k = 0; k < GRUH; k++) acc += hl[k] * Whh[k * 384 + tid];
    ghb[tid] = acc;
    __syncthreads();
    if (tid < GRUH) {
      const float* gi = gi_all + (size_t)(b * 5 + t) * 384;
      float r = 1.f / (1.f + expf(-(gi[tid] + ghb[tid])));
      float z = 1.f / (1.f + expf(-(gi[128 + tid] + ghb[128 + tid])));
      float nn = tanhf(gi[256 + tid] + r * ghb[256 + tid]);
      float hn = (1.f - z) * nn + z * hl[tid];
      go[t * GRUH + tid] = hn;
      hl[tid] = hn;
    }
  }
  __syncthreads();
  if (tid < GRUH) dout[15360 + b * GRUH + tid] = hl[tid];
  if (tid < 320) {
    int t = tid >> 6, j = tid & 63;
    float acc = fc1b[j];
    for (int k = 0; k < GRUH; k++) acc += go[t * GRUH + k] * fc1W[k * 64 + j];
    f1[t * 64 + j] = fmaxf(acc, 0.f);
  }
  __syncthreads();
  if (tid < 15) {
    int t = tid / 3, o = tid % 3;
    float v = fc2b[o];
    for (int j = 0; j < 64; j++) v += f1[t * 64 + j] * fc2W[j * 3 + o];
    dout[(b * 5 + t) * 3 + o] = v;
    float ls = log_std[o];
    ls = fminf(fmaxf(ls, -20.f), 2.f);
    dout[7680 + (b * 5 + t) * 3 + o] = expf(ls);
  }
}

extern "C" void kernel_launch(void* const* d_in, const int* in_sizes, int n_in,
                              void* d_out, int out_size, void* d_ws, size_t ws_size,
                              hipStream_t stream) {
  const float* x      = (const float*)d_in[0];
  const int*   ei     = (const int*)d_in[1];
  const float* eattr  = (const float*)d_in[2];
  const float* hstate = (const float*)d_in[3];
  const float* W1  = (const float*)d_in[4];
  const float* as1 = (const float*)d_in[5];
  const float* ad1 = (const float*)d_in[6];
  const float* We1 = (const float*)d_in[7];
  const float* ae1 = (const float*)d_in[8];
  const float* b1  = (const float*)d_in[9];
  const float* W2  = (const float*)d_in[10];
  const float* as2 = (const float*)d_in[11];
  const float* ad2 = (const float*)d_in[12];
  const float* We2 = (const float*)d_in[13];
  const float* ae2 = (const float*)d_in[14];
  const float* b2  = (const float*)d_in[15];
  const float* W3  = (const float*)d_in[16];
  const float* as3 = (const float*)d_in[17];
  const float* ad3 = (const float*)d_in[18];
  const float* We3 = (const float*)d_in[19];
  const float* ae3 = (const float*)d_in[20];
  const float* b3  = (const float*)d_in[21];
  const float* Wih = (const float*)d_in[22];
  const float* Whh = (const float*)d_in[23];
  const float* bih = (const float*)d_in[24];
  const float* bhh = (const float*)d_in[25];
  const float* fc1W = (const float*)d_in[26];
  const float* fc1b = (const float*)d_in[27];
  const float* fc2W = (const float*)d_in[28];
  const float* fc2b = (const float*)d_in[29];
  const float* lstd = (const float*)d_in[30];

  float* ws = (float*)d_ws;
  ushort_t* xbf1 = (ushort_t*)ws;                  // (NN+64)*FF = 13,139,968 us
  ushort_t* xbf2 = (ushort_t*)(ws + 6569984);      // ping-pong (layer-2 out)
  float* p = ws + 2 * 6569984;
  int*   rowp  = (int*)p;         p += 32768;      // [512][64]
  ushort_t* esrc = (ushort_t*)p;  p += 102400;     // 204,800 us
  float* eea   = p;               p += 204800;
  float* lattr = p;               p += 25600;
  float* wdot  = p;               p += 32;
  ushort_t* w2t  = (ushort_t*)p;  p += 131072;
  ushort_t* w3t  = (ushort_t*)p;  p += 131072;
  ushort_t* wiht = (ushort_t*)p;  p += 196608;
  ushort_t* cbf  = (ushort_t*)p;  p += 1310720;    // [2560][1024] bf16
  float* gi_all  = p;             p += 983040;     // [2560][384]
  float* dout = (float*)d_out;

  k_pre<<<1409, 256, 0, stream>>>(W2, W3, Wih, w2t, w3t, wiht, ei, eattr,
                                  rowp, esrc, eea, lattr,
                                  We1, ae1, We2, ae2, We3, ae3, wdot);

  // layer 1 (VALU rank-4 conv, no self loops) -> xbf1
  k_layer<<<dim3(BB, 2), 256, 0, stream>>>(nullptr, x, W1, nullptr, as1, ad1,
                                           xbf1, nullptr, rowp, esrc, eea, lattr,
                                           wdot, b1, 0, 0);
  // layer 2: reads xbf1, writes xbf2 (distinct buffers — no race)
  k_layer<<<dim3(BB, 2), 256, 0, stream>>>(xbf1, nullptr, nullptr, w2t, as2, ad2,
                                           xbf2, nullptr, rowp, esrc, eea, lattr,
                                           wdot, b2, 1, 1);
  // layer 3: reads xbf2 -> fused pool into cbf
  k_layer<<<dim3(BB, 2), 256, 0, stream>>>(xbf2, nullptr, nullptr, w3t, as3, ad3,
                                           nullptr, cbf, rowp, esrc, eea, lattr,
                                           wdot, b3, 2, 1);

  // GRU input GEMM (adds bih)
  k_bgemm<<<dim3(3, 20), 256, 0, stream>>>(cbf, wiht, bih, gi_all, 2560, 384, GRUIN);

  // GRU + heads
  k_grufc<<<BB, 384, 0, stream>>>(gi_all, hstate, Whh, bhh, fc1W, fc1b,
                                  fc2W, fc2b, lstd, dout);
}